// Round 2
// baseline (46.106 us; speedup 1.0000x reference)
//
#include <hip/hip_runtime.h>
#include <math.h>

namespace {

constexpr int BATCH = 16;
constexpr int Ww = 96;
constexpr int NP = 96 * 96;   // 9216
constexpr int NHYP = 128;
constexpr int BPB = 18;       // blocks per batch
constexpr int PXB = 512;      // pixels per block (256 threads * 2)

__device__ inline double waveSumD(double v) {
#pragma unroll
  for (int o = 32; o >= 1; o >>= 1) v += __shfl_xor(v, o, 64);
  return v;
}

// One fused kernel. Grid = 16 batches * 18 blocks, 256 threads.
// Phase 1: (redundant per block) solve 2x2 per hyp, batch stats, outlier
//          replacement -> LDS.
// Phase 2: votes. Each lane owns 2 pixels (u,v,c in regs); loop over 128
//          hyps broadcast from LDS; ballot+popcount; merge via LDS + 1
//          global atomicAdd per (b,hyp).
// Phase 3: last block of the batch (ticket) computes weights + output.
__global__ __launch_bounds__(256)
void fused_kernel(const float* __restrict__ uv, const int* __restrict__ pair,
                  int* __restrict__ counts, int* __restrict__ done,
                  float* __restrict__ out) {
  __shared__ double sYy[NHYP], sYx[NHYP];
  __shared__ double sPy[NHYP], sPx[NHYP];
  __shared__ float  sPf[2 * NHYP];   // (yy,yx) as f32, interleaved
  __shared__ float  sWm[NHYP];       // 10.0 or 1.0
  __shared__ int    sNan[NHYP];
  __shared__ int    sCnt[NHYP];
  __shared__ double shD[2];
  __shared__ int    sPrev;

  const int t = threadIdx.x;
  const int lane = t & 63;
  const int b = blockIdx.x / BPB;
  const int blk = blockIdx.x - b * BPB;
  const float* uvb = uv + (size_t)b * 2 * NP;

  // ---- pixel data for phase 2 (issue loads early) ----
  const int p0 = blk * PXB + t;
  const int p1 = p0 + 256;
  float u0 = uvb[p0], u1 = uvb[p1];
  float v0 = uvb[NP + p0], v1 = uvb[NP + p1];
  float cp0 = (float)(p0 / Ww) * u0 + (float)(p0 % Ww) * v0;
  float cp1 = (float)(p1 / Ww) * u1 + (float)(p1 % Ww) * v1;

  // ---- phase 1: solves ----
  if (t < NHYP) {
    int i0 = pair[(b * NHYP + t) * 2 + 0];
    int i1 = pair[(b * NHYP + t) * 2 + 1];
    double a0 = uvb[i0], c0 = uvb[NP + i0];
    double a1 = uvb[i1], c1 = uvb[NP + i1];
    double yy0 = (double)(i0 / Ww), xx0 = (double)(i0 % Ww);
    double yy1 = (double)(i1 / Ww), xx1 = (double)(i1 % Ww);
    double det = a1 * c0 - a0 * c1;
    double s = (a1 * (xx1 - xx0) - c1 * (yy1 - yy0)) / det;
    sYy[t] = s * a0 + yy0;
    sYx[t] = s * c0 + xx0;
    sCnt[t] = 0;
  }
  __syncthreads();

  // ---- phase 1b: stats + outlier replacement (waves 0,1 redundantly) ----
  if (t < NHYP) {
    double Yy = sYy[t], Yx = sYx[t];
    double my = waveSumD(sYy[lane] + sYy[lane + 64]) * (1.0 / NHYP);
    double mx = waveSumD(sYx[lane] + sYx[lane + 64]) * (1.0 / NHYP);
    double dy0 = sYy[lane] - my, dy1 = sYy[lane + 64] - my;
    double dx0 = sYx[lane] - mx, dx1 = sYx[lane + 64] - mx;
    double vy = waveSumD(dy0 * dy0 + dy1 * dy1) * (1.0 / (NHYP - 1));
    double vx = waveSumD(dx0 * dx0 + dx1 * dx1) * (1.0 / (NHYP - 1));
    double sdy = sqrt(vy), sdx = sqrt(vx);
    bool outl = ((Yy - my) / sdy > 2.0) || ((Yx - mx) / sdx > 2.0);
    double py = outl ? my : Yy;
    double px = outl ? mx : Yx;
    sPy[t] = py; sPx[t] = px;
    sPf[2 * t] = (float)py; sPf[2 * t + 1] = (float)px;
    // h_in_mask==1 <=> trunc(Yp) hits a lattice point <=> Yp in (-1,96)^2
    sWm[t] = (py > -1.0 && py < 96.0 && px > -1.0 && px < 96.0) ? 10.0f : 1.0f;
    sNan[t] = (isnan(py) || isnan(px)) ? 1 : 0;
  }
  __syncthreads();

  // ---- phase 2: votes (sign of (Yp-pt)·uv; normalization is sign-preserving)
  int cnt0 = 0, cnt1 = 0;
#pragma unroll 4
  for (int h = 0; h < NHYP; ++h) {
    float yy = sPf[2 * h], yx = sPf[2 * h + 1];
    bool d0 = fmaf(yy, u0, yx * v0) > cp0;   // NaN -> false, matches reference
    bool d1 = fmaf(yy, u1, yx * v1) > cp1;
    int c = __popcll(__ballot(d0)) + __popcll(__ballot(d1));
    if (h < 64) cnt0 += (lane == h) ? c : 0;
    else        cnt1 += (lane == (h - 64)) ? c : 0;
  }
  atomicAdd(&sCnt[lane], cnt0);
  atomicAdd(&sCnt[lane + 64], cnt1);
  __syncthreads();
  if (t < NHYP) atomicAdd(&counts[b * NHYP + t], sCnt[t]);

  // ---- completion ticket ----
  __syncthreads();
  __threadfence();
  if (t == 0) sPrev = atomicAdd(&done[b], 1);
  __syncthreads();
  if (sPrev != BPB - 1) return;

  // ---- phase 3: last block of batch computes the output ----
  __threadfence();
  auto bsum = [&](double v) -> double {   // sum over threads 0..127
    double r = waveSumD(v);
    __syncthreads();
    if (t < NHYP && lane == 0) shD[t >> 6] = r;
    __syncthreads();
    return shD[0] + shD[1];
  };

  double w = 0.0;
  if (t < NHYP) {
    int cv = __hip_atomic_load(&counts[b * NHYP + t], __ATOMIC_RELAXED,
                               __HIP_MEMORY_SCOPE_AGENT);
    w = (double)cv * (double)sWm[t];
  }
  double wsum = bsum(w);
  double wn = 0.0, py = 0.0, px = 0.0;
  if (t < NHYP && !sNan[t]) {
    wn = w / wsum;
    py = sPy[t];
    px = sPx[t];
  }
  double oy = bsum(py * wn);
  double ox = bsum(px * wn);
  if (t == 0) {
    out[b * 2 + 0] = (float)ox;   // weighted_mean[:, ::-1]
    out[b * 2 + 1] = (float)oy;
  }
}

}  // namespace

extern "C" void kernel_launch(void* const* d_in, const int* in_sizes, int n_in,
                              void* d_out, int out_size, void* d_ws, size_t ws_size,
                              hipStream_t stream) {
  const float* uv = (const float*)d_in[0];   // (16,2,96,96) f32
  // d_in[1] = mask, unused (all ones; never read by the reference math)
  const int* pair = (const int*)d_in[2];     // (16,128,2) i32
  float* out = (float*)d_out;                // (16,2) f32

  char* ws = (char*)d_ws;
  int* counts = (int*)ws;                    // 16*128*4 = 8192 B
  int* done   = (int*)(ws + 8192);           // 16*4     =   64 B

  hipMemsetAsync(ws, 0, 8192 + 64, stream);
  fused_kernel<<<BATCH * BPB, 256, 0, stream>>>(uv, pair, counts, done, out);
}